// Round 1
// baseline (32.205 us; speedup 1.0000x reference)
//
#include <hip/hip_runtime.h>

#define NGRID 2048
#define BATCH 4
#define CIN   16
#define COUT  32
#define NCTX  256
#define NOUT  1024

__device__ __forceinline__ float fexp2(float x) {
#if __has_builtin(__builtin_amdgcn_exp2f)
    return __builtin_amdgcn_exp2f(x);
#else
    return exp2f(x);
#endif
}

// Kernel 1: min/max over x_context and x_target -> ws[0] = x_min - 0.1, ws[1] = x_max + 0.1
__global__ __launch_bounds__(256) void minmax_kernel(const float* __restrict__ xc,
                                                     const float* __restrict__ xt,
                                                     float* __restrict__ ws) {
    int t = threadIdx.x;
    float mn = 1e30f, mx = -1e30f;
    for (int i = t; i < BATCH * NCTX; i += 256) {
        float v = xc[i];
        mn = fminf(mn, v);
        mx = fmaxf(mx, v);
    }
    for (int i = t; i < BATCH * NOUT; i += 256) {
        float v = xt[i];
        mn = fminf(mn, v);
        mx = fmaxf(mx, v);
    }
    #pragma unroll
    for (int off = 32; off; off >>= 1) {
        mn = fminf(mn, __shfl_xor(mn, off));
        mx = fmaxf(mx, __shfl_xor(mx, off));
    }
    __shared__ float smn[4], smx[4];
    int w = t >> 6;
    if ((t & 63) == 0) { smn[w] = mn; smx[w] = mx; }
    __syncthreads();
    if (t == 0) {
        mn = fminf(fminf(smn[0], smn[1]), fminf(smn[2], smn[3]));
        mx = fmaxf(fmaxf(smx[0], smx[1]), fmaxf(smx[2], smx[3]));
        ws[0] = mn - 0.1f;
        ws[1] = mx + 0.1f;
    }
}

// Kernel 2: one wave per (b, o). Each lane covers 4 consecutive grid points per
// iteration; 16 channel accumulators; butterfly reduce; lanes 0..31 apply W + b.
__global__ __launch_bounds__(64) void conv_decoder_kernel(
        const float* __restrict__ r,      // (B, CIN, NGRID)
        const float* __restrict__ xt,     // (B, NOUT)
        const float* __restrict__ sigma,  // (CIN)
        const float* __restrict__ W,      // (CIN, COUT)
        const float* __restrict__ bias,   // (COUT)
        const float* __restrict__ ws,     // [0]=x_min, [1]=x_max (adjusted)
        float* __restrict__ out) {        // (B, NOUT, COUT)
    int blk  = blockIdx.x;     // 0..B*NOUT-1
    int b    = blk >> 10;      // / NOUT
    int o    = blk & (NOUT - 1);
    int lane = threadIdx.x;    // 0..63

    float xmin = ws[0];
    float xmax = ws[1];
    float step = (xmax - xmin) * (1.0f / (float)(NGRID - 1));
    float x = xt[b * NOUT + o];

    const float LOG2E = 1.4426950408889634f;
    float a2[CIN];
    #pragma unroll
    for (int c = 0; c < CIN; ++c) {
        float s = sigma[c];
        // -0.5 / exp(2s) * log2(e), so weight = exp2(a2 * d^2) == exp(-0.5 d^2 / scale^2)
        a2[c] = -0.5f * LOG2E * fexp2(-2.0f * LOG2E * s);
    }

    float acc[CIN];
    #pragma unroll
    for (int c = 0; c < CIN; ++c) acc[c] = 0.0f;

    const float* rb = r + (size_t)b * (CIN * NGRID);

    #pragma unroll 1
    for (int k = 0; k < NGRID / 256; ++k) {   // 8 iterations
        int i0 = k * 256 + lane * 4;
        float d2[4];
        #pragma unroll
        for (int j = 0; j < 4; ++j) {
            float g = xmin + step * (float)(i0 + j);
            float d = g - x;
            d2[j] = d * d;
        }
        #pragma unroll
        for (int c = 0; c < CIN; ++c) {
            const float4 r4 = *reinterpret_cast<const float4*>(rb + c * NGRID + i0);
            float a = a2[c];
            acc[c] += r4.x * fexp2(a * d2[0]);
            acc[c] += r4.y * fexp2(a * d2[1]);
            acc[c] += r4.z * fexp2(a * d2[2]);
            acc[c] += r4.w * fexp2(a * d2[3]);
        }
    }

    // full-wave butterfly reduction: every lane ends with the total
    #pragma unroll
    for (int c = 0; c < CIN; ++c) {
        #pragma unroll
        for (int off = 32; off; off >>= 1)
            acc[c] += __shfl_xor(acc[c], off);
    }

    if (lane < COUT) {
        float s = bias[lane];
        #pragma unroll
        for (int c = 0; c < CIN; ++c)
            s += acc[c] * W[c * COUT + lane];
        out[((size_t)b * NOUT + o) * COUT + lane] = s;
    }
}

extern "C" void kernel_launch(void* const* d_in, const int* in_sizes, int n_in,
                              void* d_out, int out_size, void* d_ws, size_t ws_size,
                              hipStream_t stream) {
    const float* r  = (const float*)d_in[0];  // (4,16,2048)
    const float* xc = (const float*)d_in[1];  // (4,256,1)
    // d_in[2] = y_context — unused by the reference
    const float* xt = (const float*)d_in[3];  // (4,1024,1)
    const float* sg = (const float*)d_in[4];  // (16)
    const float* W  = (const float*)d_in[5];  // (16,32)
    const float* bs = (const float*)d_in[6];  // (32)
    float* out = (float*)d_out;               // (4,1024,32) f32
    float* ws  = (float*)d_ws;

    minmax_kernel<<<1, 256, 0, stream>>>(xc, xt, ws);
    conv_decoder_kernel<<<BATCH * NOUT, 64, 0, stream>>>(r, xt, sg, W, bs, ws, out);
}

// Round 2
// 20.773 us; speedup vs baseline: 1.5503x; 1.5503x over previous
//
#include <hip/hip_runtime.h>

#define NGRID 2048
#define BATCH 4
#define CIN   16
#define COUT  32
#define NCTX  256
#define NOUT  1024
#define OPW   4                      // targets per wave
#define NBLK  (BATCH * NOUT / OPW)   // 1024 blocks x 64 threads

__device__ __forceinline__ float fexp2(float x) {
#if __has_builtin(__builtin_amdgcn_exp2f)
    return __builtin_amdgcn_exp2f(x);
#else
    return exp2f(x);
#endif
}

// Single fused kernel: each wave (64 lanes) handles one (b, group of 4 targets).
// 1) redundant min/max over x_context + x_target (L2-hot, deterministic)
// 2) main loop: one exp per (target, gridpoint) when sigma is channel-uniform
//    (generic per-channel fallback otherwise); each float4 r-load feeds 4 targets
// 3) 6-stage value-routing fold -> lane v holds total of value v = j*16+c
// 4) tiny LDS transpose + 16->32 W matmul epilogue
__global__ __launch_bounds__(64) void conv_decoder_fused(
        const float* __restrict__ r,      // (B, CIN, NGRID)
        const float* __restrict__ xc,     // (B, NCTX)
        const float* __restrict__ xt,     // (B, NOUT)
        const float* __restrict__ sigma,  // (CIN)
        const float* __restrict__ W,      // (CIN, COUT)
        const float* __restrict__ bias,   // (COUT)
        float* __restrict__ out) {        // (B, NOUT, COUT)
    const int lane = threadIdx.x;
    const int blk  = blockIdx.x;
    const int b    = blk >> 8;           // NOUT/OPW = 256 groups per batch
    const int og   = blk & 255;

    // ---- fused min/max over all x (5120 floats, L2-resident) ----
    float mn = 1e30f, mx = -1e30f;
    #pragma unroll
    for (int i = 0; i < BATCH * NCTX; i += 64 * 4) {
        float4 v = *reinterpret_cast<const float4*>(xc + i + lane * 4);
        mn = fminf(mn, fminf(fminf(v.x, v.y), fminf(v.z, v.w)));
        mx = fmaxf(mx, fmaxf(fmaxf(v.x, v.y), fmaxf(v.z, v.w)));
    }
    #pragma unroll
    for (int i = 0; i < BATCH * NOUT; i += 64 * 4) {
        float4 v = *reinterpret_cast<const float4*>(xt + i + lane * 4);
        mn = fminf(mn, fminf(fminf(v.x, v.y), fminf(v.z, v.w)));
        mx = fmaxf(mx, fmaxf(fmaxf(v.x, v.y), fmaxf(v.z, v.w)));
    }
    #pragma unroll
    for (int off = 32; off; off >>= 1) {
        mn = fminf(mn, __shfl_xor(mn, off));
        mx = fmaxf(mx, __shfl_xor(mx, off));
    }
    const float xmin = mn - 0.1f;
    const float xmax = mx + 0.1f;
    const float step = (xmax - xmin) * (1.0f / (float)(NGRID - 1));

    // ---- per-channel exponent coefficients; uniformity check ----
    const float LOG2E = 1.4426950408889634f;
    float a2[CIN];
    #pragma unroll
    for (int c = 0; c < CIN; ++c) {
        float s = sigma[c];
        a2[c] = -0.5f * LOG2E * fexp2(-2.0f * LOG2E * s);  // exp2(a2*d^2) == exp(-0.5 d^2/scale^2)
    }
    bool uni = true;
    #pragma unroll
    for (int c = 1; c < CIN; ++c) uni = uni && (a2[c] == a2[0]);

    float x[OPW];
    #pragma unroll
    for (int j = 0; j < OPW; ++j) x[j] = xt[b * NOUT + og * OPW + j];

    float acc[OPW * CIN];   // value v = j*16 + c
    #pragma unroll
    for (int v = 0; v < OPW * CIN; ++v) acc[v] = 0.0f;

    const float* rb = r + (size_t)b * (CIN * NGRID);

    if (uni) {
        const float a = a2[0];
        #pragma unroll 2
        for (int k = 0; k < NGRID / 256; ++k) {    // 8 iterations
            const int i0 = k * 256 + lane * 4;
            float w[OPW][4];
            #pragma unroll
            for (int p = 0; p < 4; ++p) {
                float g = xmin + step * (float)(i0 + p);
                #pragma unroll
                for (int j = 0; j < OPW; ++j) {
                    float d = g - x[j];
                    w[j][p] = fexp2(a * d * d);
                }
            }
            #pragma unroll
            for (int h = 0; h < 2; ++h) {          // two batches of 8 channels
                float4 rv[8];
                #pragma unroll
                for (int c8 = 0; c8 < 8; ++c8)
                    rv[c8] = *reinterpret_cast<const float4*>(rb + (h * 8 + c8) * NGRID + i0);
                #pragma unroll
                for (int c8 = 0; c8 < 8; ++c8) {
                    const int c = h * 8 + c8;
                    #pragma unroll
                    for (int j = 0; j < OPW; ++j) {
                        acc[j * CIN + c] += rv[c8].x * w[j][0];
                        acc[j * CIN + c] += rv[c8].y * w[j][1];
                        acc[j * CIN + c] += rv[c8].z * w[j][2];
                        acc[j * CIN + c] += rv[c8].w * w[j][3];
                    }
                }
            }
        }
    } else {
        // generic fallback: per-channel exponents (correct for any sigma)
        #pragma unroll 1
        for (int k = 0; k < NGRID / 256; ++k) {
            const int i0 = k * 256 + lane * 4;
            float d2[OPW][4];
            #pragma unroll
            for (int p = 0; p < 4; ++p) {
                float g = xmin + step * (float)(i0 + p);
                #pragma unroll
                for (int j = 0; j < OPW; ++j) {
                    float d = g - x[j];
                    d2[j][p] = d * d;
                }
            }
            #pragma unroll
            for (int c = 0; c < CIN; ++c) {
                float4 rv = *reinterpret_cast<const float4*>(rb + c * NGRID + i0);
                float a = a2[c];
                #pragma unroll
                for (int j = 0; j < OPW; ++j) {
                    acc[j * CIN + c] += rv.x * fexp2(a * d2[j][0]);
                    acc[j * CIN + c] += rv.y * fexp2(a * d2[j][1]);
                    acc[j * CIN + c] += rv.z * fexp2(a * d2[j][2]);
                    acc[j * CIN + c] += rv.w * fexp2(a * d2[j][3]);
                }
            }
        }
    }

    // ---- 6-stage value-routing fold: lane L ends with total of value L ----
    #pragma unroll
    for (int st = 0; st < 6; ++st) {
        const int off = 32 >> st;
        const bool hi = (lane & off) != 0;
        #pragma unroll
        for (int v = 0; v < (32 >> st); ++v) {
            float keep = hi ? acc[v + (32 >> st)] : acc[v];
            float send = hi ? acc[v] : acc[v + (32 >> st)];
            acc[v] = keep + __shfl_xor(send, off);
        }
    }

    // ---- LDS transpose + W matmul epilogue ----
    __shared__ float sm[64];
    sm[lane] = acc[0];
    __syncthreads();

    const int j    = lane >> 4;
    const int cout = lane & 15;
    float o0 = bias[cout];
    float o1 = bias[cout + 16];
    #pragma unroll
    for (int c = 0; c < CIN; ++c) {
        float z = sm[j * 16 + c];
        o0 += z * W[c * COUT + cout];
        o1 += z * W[c * COUT + cout + 16];
    }
    const size_t orow = ((size_t)b * NOUT + og * OPW + j) * COUT;
    out[orow + cout]      = o0;
    out[orow + cout + 16] = o1;
}

extern "C" void kernel_launch(void* const* d_in, const int* in_sizes, int n_in,
                              void* d_out, int out_size, void* d_ws, size_t ws_size,
                              hipStream_t stream) {
    const float* r  = (const float*)d_in[0];  // (4,16,2048)
    const float* xc = (const float*)d_in[1];  // (4,256,1)
    // d_in[2] = y_context — unused by the reference
    const float* xt = (const float*)d_in[3];  // (4,1024,1)
    const float* sg = (const float*)d_in[4];  // (16)
    const float* W  = (const float*)d_in[5];  // (16,32)
    const float* bs = (const float*)d_in[6];  // (32)
    float* out = (float*)d_out;               // (4,1024,32) f32

    conv_decoder_fused<<<NBLK, 64, 0, stream>>>(r, xc, xt, sg, W, bs, out);
}

// Round 3
// 19.532 us; speedup vs baseline: 1.6489x; 1.0636x over previous
//
#include <hip/hip_runtime.h>

#define NGRID 2048
#define BATCH 4
#define CIN   16
#define COUT  32
#define NCTX  256
#define NOUT  1024
#define OPW   4                      // targets per block
#define WAVES 4                      // waves per block; wave w owns grid chunk w*512..w*512+511
#define NBLK  (BATCH * NOUT / OPW)   // 1024 blocks x 256 threads

__device__ __forceinline__ float fexp2(float x) {
#if __has_builtin(__builtin_amdgcn_exp2f)
    return __builtin_amdgcn_exp2f(x);
#else
    return exp2f(x);
#endif
}

__global__ __launch_bounds__(256) void conv_decoder_fused(
        const float* __restrict__ r,      // (B, CIN, NGRID)
        const float* __restrict__ xc,     // (B, NCTX)
        const float* __restrict__ xt,     // (B, NOUT)
        const float* __restrict__ sigma,  // (CIN)
        const float* __restrict__ W,      // (CIN, COUT)
        const float* __restrict__ bias,   // (COUT)
        float* __restrict__ out) {        // (B, NOUT, COUT)
    const int tid  = threadIdx.x;
    const int lane = tid & 63;
    const int wv   = tid >> 6;
    const int blk  = blockIdx.x;
    const int b    = blk >> 8;           // NOUT/OPW = 256 groups per batch
    const int og   = blk & 255;

    // ---- cooperative block-wide min/max over xc (1024 f) + xt (4096 f) ----
    float mn, mx;
    {
        float4 v = *reinterpret_cast<const float4*>(xc + tid * 4);
        mn = fminf(fminf(v.x, v.y), fminf(v.z, v.w));
        mx = fmaxf(fmaxf(v.x, v.y), fmaxf(v.z, v.w));
        #pragma unroll
        for (int k = 0; k < 4; ++k) {
            float4 u = *reinterpret_cast<const float4*>(xt + (k * 256 + tid) * 4);
            mn = fminf(mn, fminf(fminf(u.x, u.y), fminf(u.z, u.w)));
            mx = fmaxf(mx, fmaxf(fmaxf(u.x, u.y), fmaxf(u.z, u.w)));
        }
        #pragma unroll
        for (int off = 32; off; off >>= 1) {
            mn = fminf(mn, __shfl_xor(mn, off));
            mx = fmaxf(mx, __shfl_xor(mx, off));
        }
    }
    __shared__ float smn[WAVES], smx[WAVES];
    __shared__ float part[WAVES][64];
    if (lane == 0) { smn[wv] = mn; smx[wv] = mx; }
    __syncthreads();
    mn = fminf(fminf(smn[0], smn[1]), fminf(smn[2], smn[3]));
    mx = fmaxf(fmaxf(smx[0], smx[1]), fmaxf(smx[2], smx[3]));
    const float xmin = mn - 0.1f;
    const float step = ((mx + 0.1f) - xmin) * (1.0f / (float)(NGRID - 1));

    // ---- per-channel exponent coefficients; uniformity check ----
    const float LOG2E = 1.4426950408889634f;
    float a2[CIN];
    #pragma unroll
    for (int c = 0; c < CIN; ++c) {
        float s = sigma[c];
        a2[c] = -0.5f * LOG2E * fexp2(-2.0f * LOG2E * s);  // exp2(a2*d^2) == exp(-0.5 d^2/scale^2)
    }
    bool uni = true;
    #pragma unroll
    for (int c = 1; c < CIN; ++c) uni = uni && (a2[c] == a2[0]);

    float x[OPW];
    #pragma unroll
    for (int j = 0; j < OPW; ++j) x[j] = xt[b * NOUT + og * OPW + j];

    float acc[OPW * CIN];   // value v = j*16 + c (partial over this wave's 512 grid points)
    #pragma unroll
    for (int v = 0; v < OPW * CIN; ++v) acc[v] = 0.0f;

    const float* rb = r + (size_t)b * (CIN * NGRID);

    if (uni) {
        const float a = a2[0];           // a <= 0
        const float s = sqrtf(-a);       // weight = exp2(-(s*g - s*x)^2)
        float sx[OPW];
        #pragma unroll
        for (int j = 0; j < OPW; ++j) sx[j] = s * x[j];

        #pragma unroll 1
        for (int k = 0; k < 2; ++k) {    // 2 iterations of 256 points per wave
            const int i0 = wv * 512 + k * 256 + lane * 4;
            float wgt[OPW][4];
            #pragma unroll
            for (int p = 0; p < 4; ++p) {
                float sg = s * (xmin + step * (float)(i0 + p));
                #pragma unroll
                for (int j = 0; j < OPW; ++j) {
                    float d = sg - sx[j];
                    wgt[j][p] = fexp2(-(d * d));
                }
            }
            #pragma unroll
            for (int h = 0; h < 2; ++h) {          // two batches of 8 channels
                float4 rv[8];
                #pragma unroll
                for (int c8 = 0; c8 < 8; ++c8)
                    rv[c8] = *reinterpret_cast<const float4*>(rb + (h * 8 + c8) * NGRID + i0);
                #pragma unroll
                for (int c8 = 0; c8 < 8; ++c8) {
                    const int c = h * 8 + c8;
                    #pragma unroll
                    for (int j = 0; j < OPW; ++j) {
                        acc[j * CIN + c] += rv[c8].x * wgt[j][0];
                        acc[j * CIN + c] += rv[c8].y * wgt[j][1];
                        acc[j * CIN + c] += rv[c8].z * wgt[j][2];
                        acc[j * CIN + c] += rv[c8].w * wgt[j][3];
                    }
                }
            }
        }
    } else {
        // generic fallback: per-channel exponents (correct for any sigma)
        #pragma unroll 1
        for (int k = 0; k < 2; ++k) {
            const int i0 = wv * 512 + k * 256 + lane * 4;
            float d2[OPW][4];
            #pragma unroll
            for (int p = 0; p < 4; ++p) {
                float g = xmin + step * (float)(i0 + p);
                #pragma unroll
                for (int j = 0; j < OPW; ++j) {
                    float d = g - x[j];
                    d2[j][p] = d * d;
                }
            }
            #pragma unroll
            for (int c = 0; c < CIN; ++c) {
                float4 rv = *reinterpret_cast<const float4*>(rb + c * NGRID + i0);
                float a = a2[c];
                #pragma unroll
                for (int j = 0; j < OPW; ++j) {
                    acc[j * CIN + c] += rv.x * fexp2(a * d2[j][0]);
                    acc[j * CIN + c] += rv.y * fexp2(a * d2[j][1]);
                    acc[j * CIN + c] += rv.z * fexp2(a * d2[j][2]);
                    acc[j * CIN + c] += rv.w * fexp2(a * d2[j][3]);
                }
            }
        }
    }

    // ---- 6-stage value-routing fold: lane L ends with this wave's total of value L ----
    #pragma unroll
    for (int st = 0; st < 6; ++st) {
        const int off = 32 >> st;
        const bool hi = (lane & off) != 0;
        #pragma unroll
        for (int v = 0; v < (32 >> st); ++v) {
            float keep = hi ? acc[v + (32 >> st)] : acc[v];
            float send = hi ? acc[v] : acc[v + (32 >> st)];
            acc[v] = keep + __shfl_xor(send, off);
        }
    }

    // ---- cross-wave combine + per-wave epilogue (wave wv handles target wv) ----
    part[wv][lane] = acc[0];
    __syncthreads();
    float tot = part[0][lane] + part[1][lane] + part[2][lane] + part[3][lane];
    // wave wv needs values v = wv*16 + c, which live on lanes wv*16+c of every wave
    float z[CIN];
    #pragma unroll
    for (int c = 0; c < CIN; ++c)
        z[c] = __shfl(tot, wv * 16 + c);

    if (lane < COUT) {
        float o = bias[lane];
        #pragma unroll
        for (int c = 0; c < CIN; ++c)
            o += z[c] * W[c * COUT + lane];
        out[((size_t)b * NOUT + og * OPW + wv) * COUT + lane] = o;
    }
}

extern "C" void kernel_launch(void* const* d_in, const int* in_sizes, int n_in,
                              void* d_out, int out_size, void* d_ws, size_t ws_size,
                              hipStream_t stream) {
    const float* r  = (const float*)d_in[0];  // (4,16,2048)
    const float* xc = (const float*)d_in[1];  // (4,256,1)
    // d_in[2] = y_context — unused by the reference
    const float* xt = (const float*)d_in[3];  // (4,1024,1)
    const float* sg = (const float*)d_in[4];  // (16)
    const float* W  = (const float*)d_in[5];  // (16,32)
    const float* bs = (const float*)d_in[6];  // (32)
    float* out = (float*)d_out;               // (4,1024,32) f32

    conv_decoder_fused<<<NBLK, 256, 0, stream>>>(r, xc, xt, sg, W, bs, out);
}